// Round 12
// baseline (576.616 us; speedup 1.0000x reference)
//
#include <hip/hip_runtime.h>

typedef __attribute__((ext_vector_type(8))) _Float16 half8;
typedef __attribute__((ext_vector_type(4))) _Float16 half4;
typedef __attribute__((ext_vector_type(4))) float f32x4;

#define SEQ 2048
#define DMODEL 1024
#define NHEAD 16
#define HEADD 64
#define NBH 32          // B * NHEAD
#define LUTW 4096

// raw barrier: orders LDS only; global loads/stores stay in flight across it
#define LDS_BAR() do {                                   \
    __builtin_amdgcn_sched_barrier(0);                   \
    asm volatile("s_waitcnt lgkmcnt(0)" ::: "memory");   \
    __builtin_amdgcn_sched_barrier(0);                   \
    __builtin_amdgcn_s_barrier();                        \
    __builtin_amdgcn_sched_barrier(0);                   \
} while (0)

// ---------------- T5 relative position bucket ----------------
__device__ __forceinline__ int rel_bucket(int rel) {
    int ret = (rel > 0) ? 16 : 0;
    int rp = rel < 0 ? -rel : rel;
    if (rp < 8) return ret + rp;
    float x = logf((float)rp * 0.125f) / 2.7725887f * 8.0f;
    int v = 8 + (int)x;
    v = v < 15 ? v : 15;
    return ret + v;
}

// ---------------- prep: all casts + bias LUT in one launch ----------------
__global__ __launch_bounds__(256) void prep_kernel(const float* __restrict__ hs,
                                                   const float* __restrict__ Wq,
                                                   const float* __restrict__ Wk,
                                                   const float* __restrict__ Wv,
                                                   const float* __restrict__ Wo,
                                                   const float* __restrict__ rel_bias,
                                                   _Float16* __restrict__ Xh,
                                                   _Float16* __restrict__ Wqh,
                                                   _Float16* __restrict__ Wkh,
                                                   _Float16* __restrict__ Wvh,
                                                   _Float16* __restrict__ Woh,
                                                   float* __restrict__ lut) {
    int bid = blockIdx.x;
    if (bid < 4096) {
        const float* in;
        _Float16* out;
        int base;
        if (bid < 2048)      { in = hs; out = Xh;  base = bid; }
        else if (bid < 2560) { in = Wq; out = Wqh; base = bid - 2048; }
        else if (bid < 3072) { in = Wk; out = Wkh; base = bid - 2560; }
        else if (bid < 3584) { in = Wv; out = Wvh; base = bid - 3072; }
        else                 { in = Wo; out = Woh; base = bid - 3584; }
        int i = (base * 256 + threadIdx.x) * 8;
        f32x4 a = *(const f32x4*)(in + i);
        f32x4 b = *(const f32x4*)(in + i + 4);
        half8 r;
        r[0] = (_Float16)a[0]; r[1] = (_Float16)a[1];
        r[2] = (_Float16)a[2]; r[3] = (_Float16)a[3];
        r[4] = (_Float16)b[0]; r[5] = (_Float16)b[1];
        r[6] = (_Float16)b[2]; r[7] = (_Float16)b[3];
        *(half8*)(out + i) = r;
    } else {
        int i = (bid - 4096) * 256 + threadIdx.x;   // 16 * 4096
        int h = i >> 12;
        int idx = i & (LUTW - 1);
        int rel = idx - 2047;
        int b = rel_bucket(rel);
        lut[i] = rel_bias[b * NHEAD + h];
    }
}

// ---------------- fused Q/K/V projection: direct-global (L2-resident inputs) ----------------
__global__ __launch_bounds__(256) void proj3_kernel(const _Float16* __restrict__ Xh,
                                                    const _Float16* __restrict__ Wqh,
                                                    const _Float16* __restrict__ Wkh,
                                                    const _Float16* __restrict__ Wvh,
                                                    _Float16* __restrict__ Qh,
                                                    _Float16* __restrict__ Kh,
                                                    _Float16* __restrict__ Vt) {
    int z = blockIdx.z;
    const _Float16* B = (z == 0) ? Wqh : (z == 1) ? Wkh : Wvh;
    int l = threadIdx.x & 63, w = threadIdx.x >> 6;
    int row0 = blockIdx.y * 128 + (w >> 1) * 64;
    int col0 = blockIdx.x * 128 + (w & 1) * 64;
    int ar = l & 15, ak = (l >> 4) * 8;
    f32x4 acc[4][4] = {};
    for (int k0 = 0; k0 < DMODEL; k0 += 32) {
        half8 af[4], bf[4];
#pragma unroll
        for (int mi = 0; mi < 4; mi++)
            af[mi] = *(const half8*)(Xh + (size_t)(row0 + mi * 16 + ar) * DMODEL + k0 + ak);
#pragma unroll
        for (int ni = 0; ni < 4; ni++)
            bf[ni] = *(const half8*)(B + (size_t)(col0 + ni * 16 + ar) * DMODEL + k0 + ak);
#pragma unroll
        for (int mi = 0; mi < 4; mi++)
#pragma unroll
            for (int ni = 0; ni < 4; ni++)
                acc[mi][ni] = __builtin_amdgcn_mfma_f32_16x16x32_f16(af[mi], bf[ni], acc[mi][ni], 0, 0, 0);
    }
    int cr = (l >> 4) * 4, cc = l & 15;
    if (z < 2) {
        _Float16* C = z == 0 ? Qh : Kh;
#pragma unroll
        for (int mi = 0; mi < 4; mi++)
#pragma unroll
            for (int ni = 0; ni < 4; ni++) {
                int c = col0 + ni * 16 + cc;
#pragma unroll
                for (int j = 0; j < 4; j++)
                    C[(size_t)(row0 + mi * 16 + cr + j) * DMODEL + c] = (_Float16)acc[mi][ni][j];
            }
    } else {
#pragma unroll
        for (int mi = 0; mi < 4; mi++)
#pragma unroll
            for (int ni = 0; ni < 4; ni++) {
                int c = col0 + ni * 16 + cc;
                int h = c >> 6, hd = c & 63;
                int r = row0 + mi * 16 + cr;
                int b = r >> 11, s0 = r & 2047;
                half4 pk;
#pragma unroll
                for (int j = 0; j < 4; j++) pk[j] = (_Float16)acc[mi][ni][j];
                *(half4*)(Vt + (size_t)((b * NHEAD + h) * HEADD + hd) * SEQ + s0) = pk;
            }
    }
}

// ---------------- output projection: direct-global, fp32 C ----------------
__global__ __launch_bounds__(256) void outgemm_kernel(const _Float16* __restrict__ A,
                                                      const _Float16* __restrict__ B,
                                                      float* __restrict__ C) {
    int l = threadIdx.x & 63, w = threadIdx.x >> 6;
    int row0 = blockIdx.y * 128 + (w >> 1) * 64;
    int col0 = blockIdx.x * 128 + (w & 1) * 64;
    int ar = l & 15, ak = (l >> 4) * 8;
    f32x4 acc[4][4] = {};
    for (int k0 = 0; k0 < DMODEL; k0 += 32) {
        half8 af[4], bf[4];
#pragma unroll
        for (int mi = 0; mi < 4; mi++)
            af[mi] = *(const half8*)(A + (size_t)(row0 + mi * 16 + ar) * DMODEL + k0 + ak);
#pragma unroll
        for (int ni = 0; ni < 4; ni++)
            bf[ni] = *(const half8*)(B + (size_t)(col0 + ni * 16 + ar) * DMODEL + k0 + ak);
#pragma unroll
        for (int mi = 0; mi < 4; mi++)
#pragma unroll
            for (int ni = 0; ni < 4; ni++)
                acc[mi][ni] = __builtin_amdgcn_mfma_f32_16x16x32_f16(af[mi], bf[ni], acc[mi][ni], 0, 0, 0);
    }
    int cr = (l >> 4) * 4, cc = l & 15;
#pragma unroll
    for (int mi = 0; mi < 4; mi++)
#pragma unroll
        for (int ni = 0; ni < 4; ni++) {
            int c = col0 + ni * 16 + cc;
#pragma unroll
            for (int j = 0; j < 4; j++)
                C[(size_t)(row0 + mi * 16 + cr + j) * DMODEL + c] = acc[mi][ni][j];
        }
}

// ---------------- fused attention (R8 structure + plain stores + no-max softmax) ----------------
// no-max: |scores| < ~50 << 88 -> exp(s) safe in fp32; masked -> 0 exactly.
__global__ __launch_bounds__(256) void attn_kernel(const _Float16* __restrict__ Q,
                                                   const _Float16* __restrict__ Kg,
                                                   const _Float16* __restrict__ Vg,
                                                   const float* __restrict__ lut,
                                                   const int* __restrict__ mask,
                                                   float* __restrict__ wts,
                                                   float* __restrict__ posb,
                                                   _Float16* __restrict__ attn0) {
    __shared__ _Float16 Kt[64][68];     // padded: conflict-free
    __shared__ _Float16 Vl[64][68];
    __shared__ _Float16 Pl[4][16][72];  // per-wave P staging
    int tid = threadIdx.x;
    int l = tid & 63, w = tid >> 6;
    int bid = blockIdx.x;               // 1024 blocks
    int xcd = bid & 7, idx = bid >> 3;
    int bh = (idx >> 5) * 8 + xcd;      // XCD-pinned K/V
    int qblk = idx & 31;
    int b = bh >> 4, h = bh & 15;
    int qbase = qblk * 64 + w * 16;
    size_t hoff = (size_t)(b * SEQ) * DMODEL + h * HEADD;
    int ar = l & 15, g = l >> 4, ak = g * 8;
    const float* luth = lut + h * LUTW;
    float* ob = wts + (size_t)bh * SEQ * SEQ;
    int q = qbase + ar;

    int sr = tid >> 2, sc = (tid & 3) * 16;
    const _Float16* Ksrc = Kg + hoff + sc;
    const _Float16* Vsrc = Vg + ((size_t)bh * HEADD + sr) * SEQ + sc;

    half8 qf[2];
#pragma unroll
    for (int kk = 0; kk < 2; kk++)
        qf[kk] = *(const half8*)(Q + hoff + (size_t)q * DMODEL + kk * 32 + ak);

    // ---------- phase 1: denominator sum (no max tracking) ----------
    half8 s0 = *(const half8*)(Ksrc + (size_t)sr * DMODEL);
    half8 s1 = *(const half8*)(Ksrc + (size_t)sr * DMODEL + 8);
    float lsum = 0.f;
    for (int k0 = 0; k0 < SEQ; k0 += 64) {
        *(half8*)&Kt[sr][sc] = s0;
        *(half8*)&Kt[sr][sc + 8] = s1;
        LDS_BAR();
        if (k0 + 64 < SEQ) {   // issue next K tile early; spans the barriers
            s0 = *(const half8*)(Ksrc + (size_t)(k0 + 64 + sr) * DMODEL);
            s1 = *(const half8*)(Ksrc + (size_t)(k0 + 64 + sr) * DMODEL + 8);
        }
        f32x4 acc[4] = {};
#pragma unroll
        for (int ni = 0; ni < 4; ni++)
#pragma unroll
            for (int kk = 0; kk < 2; kk++) {
                half8 kf = *(const half8*)&Kt[ni * 16 + ar][kk * 32 + ak];
                acc[ni] = __builtin_amdgcn_mfma_f32_16x16x32_f16(kf, qf[kk], acc[ni], 0, 0, 0);
            }
        LDS_BAR();
        float p0 = 0.f, p1 = 0.f, p2 = 0.f, p3 = 0.f;
#pragma unroll
        for (int ni = 0; ni < 4; ni++) {
            int kcol = k0 + ni * 16 + g * 4;
            int4 mk = *(const int4*)(mask + b * SEQ + kcol);
            const int* mp = (const int*)&mk;
            f32x4 lb4;
            __builtin_memcpy(&lb4, luth + kcol - q + 2047, 16);
            p0 += mp[0] ? __expf(acc[ni][0] + lb4[0]) : 0.f;
            p1 += mp[1] ? __expf(acc[ni][1] + lb4[1]) : 0.f;
            p2 += mp[2] ? __expf(acc[ni][2] + lb4[2]) : 0.f;
            p3 += mp[3] ? __expf(acc[ni][3] + lb4[3]) : 0.f;
        }
        lsum += (p0 + p1) + (p2 + p3);
    }
    // prefetch phase-2 tile 0 (K and V) before the cross-lane reduction
    half8 t0 = *(const half8*)(Ksrc + (size_t)sr * DMODEL);
    half8 t1 = *(const half8*)(Ksrc + (size_t)sr * DMODEL + 8);
    half8 v0 = *(const half8*)(Vsrc);
    half8 v1 = *(const half8*)(Vsrc + 8);
    lsum += __shfl_xor(lsum, 16);
    lsum += __shfl_xor(lsum, 32);
    float invl = 1.0f / lsum;
    LDS_BAR();   // phase boundary: all waves done with phase-1 Kt

    // ---------- phase 2: recompute -> weights (+posbias) + PV ----------
    f32x4 oacc[4] = {};
    for (int k0 = 0; k0 < SEQ; k0 += 64) {
        *(half8*)&Kt[sr][sc] = t0;
        *(half8*)&Kt[sr][sc + 8] = t1;
        *(half8*)&Vl[sr][sc] = v0;
        *(half8*)&Vl[sr][sc + 8] = v1;
        LDS_BAR();
        if (k0 + 64 < SEQ) {   // issue next K+V tiles early; spans barriers
            t0 = *(const half8*)(Ksrc + (size_t)(k0 + 64 + sr) * DMODEL);
            t1 = *(const half8*)(Ksrc + (size_t)(k0 + 64 + sr) * DMODEL + 8);
            v0 = *(const half8*)(Vsrc + k0 + 64);
            v1 = *(const half8*)(Vsrc + k0 + 64 + 8);
        }
        f32x4 acc[4] = {};
#pragma unroll
        for (int ni = 0; ni < 4; ni++)
#pragma unroll
            for (int kk = 0; kk < 2; kk++) {
                half8 kf = *(const half8*)&Kt[ni * 16 + ar][kk * 32 + ak];
                acc[ni] = __builtin_amdgcn_mfma_f32_16x16x32_f16(kf, qf[kk], acc[ni], 0, 0, 0);
            }
        int pbsel = (k0 < SEQ / 2) ? 0 : 1;   // balance posbias stores across b
#pragma unroll
        for (int ni = 0; ni < 4; ni++) {
            int kcol = k0 + ni * 16 + g * 4;
            int4 mk = *(const int4*)(mask + b * SEQ + kcol);
            const int* mp = (const int*)&mk;
            f32x4 lb4;
            __builtin_memcpy(&lb4, luth + kcol - q + 2047, 16);
            f32x4 wv;
#pragma unroll
            for (int j = 0; j < 4; j++)
                wv[j] = mp[j] ? __expf(acc[ni][j] + lb4[j]) * invl : 0.f;
            *(f32x4*)(ob + (size_t)q * SEQ + kcol) = wv;           // plain store (L2)
            if (b == pbsel)
                *(f32x4*)(posb + (size_t)h * SEQ * SEQ + (size_t)q * SEQ + kcol) = lb4;
            half4 ph;
#pragma unroll
            for (int j = 0; j < 4; j++) ph[j] = (_Float16)wv[j];
            *(half4*)&Pl[w][ar][ni * 16 + g * 4] = ph;
        }
        // PV: O[q,hd] += P[q,s] * V[s,hd]  (V from LDS)
#pragma unroll
        for (int kk2 = 0; kk2 < 2; kk2++) {
            half8 pa = *(half8*)&Pl[w][ar][kk2 * 32 + g * 8];
#pragma unroll
            for (int ni = 0; ni < 4; ni++) {
                half8 vf = *(const half8*)&Vl[ni * 16 + ar][kk2 * 32 + g * 8];
                oacc[ni] = __builtin_amdgcn_mfma_f32_16x16x32_f16(pa, vf, oacc[ni], 0, 0, 0);
            }
        }
        LDS_BAR();
    }
#pragma unroll
    for (int ni = 0; ni < 4; ni++)
#pragma unroll
        for (int j = 0; j < 4; j++)
            attn0[(size_t)(b * SEQ + qbase + g * 4 + j) * DMODEL + h * HEADD + ni * 16 + ar] =
                (_Float16)oacc[ni][j];
}

extern "C" void kernel_launch(void* const* d_in, const int* in_sizes, int n_in,
                              void* d_out, int out_size, void* d_ws, size_t ws_size,
                              hipStream_t stream) {
    const float* hs = (const float*)d_in[0];
    const int* mask = (const int*)d_in[1];
    const float* Wq = (const float*)d_in[2];
    const float* Wk = (const float*)d_in[3];
    const float* Wv = (const float*)d_in[4];
    const float* Wo = (const float*)d_in[5];
    const float* rel_bias = (const float*)d_in[6];

    float* out_attn = (float*)d_out;                       // [2,2048,1024]
    float* out_wts = out_attn + (size_t)2 * SEQ * DMODEL;  // [2,16,2048,2048]
    float* out_posb = out_wts + (size_t)NBH * SEQ * SEQ;   // [1,16,2048,2048]

    char* ws = (char*)d_ws;
    size_t off = 0;
    auto carve = [&](size_t bytes) { void* p = ws + off; off += (bytes + 255) & ~(size_t)255; return p; };
    _Float16* Xh  = (_Float16*)carve((size_t)2 * SEQ * DMODEL * 2);
    _Float16* Wqh = (_Float16*)carve((size_t)DMODEL * DMODEL * 2);
    _Float16* Wkh = (_Float16*)carve((size_t)DMODEL * DMODEL * 2);
    _Float16* Wvh = (_Float16*)carve((size_t)DMODEL * DMODEL * 2);
    _Float16* Woh = (_Float16*)carve((size_t)DMODEL * DMODEL * 2);
    _Float16* Qh  = (_Float16*)carve((size_t)2 * SEQ * DMODEL * 2);
    _Float16* Kh  = (_Float16*)carve((size_t)2 * SEQ * DMODEL * 2);
    _Float16* Vt  = (_Float16*)carve((size_t)NBH * HEADD * SEQ * 2);
    _Float16* A0h = (_Float16*)carve((size_t)2 * SEQ * DMODEL * 2);
    float* lut    = (float*)carve((size_t)NHEAD * LUTW * 4);

    // 1. prep: casts + lut
    prep_kernel<<<4352, 256, 0, stream>>>(hs, Wq, Wk, Wv, Wo, rel_bias,
                                          Xh, Wqh, Wkh, Wvh, Woh, lut);

    // 2. Q/K/V projections (direct-global GEMM; inputs L2-resident)
    dim3 pg(DMODEL / 128, (2 * SEQ) / 128, 3);
    proj3_kernel<<<pg, 256, 0, stream>>>(Xh, Wqh, Wkh, Wvh, Qh, Kh, Vt);

    // 3. fused attention
    attn_kernel<<<1024, 256, 0, stream>>>(Qh, Kh, Vt, lut, mask, out_wts, out_posb, A0h);

    // 4. output projection (direct-global GEMM)
    dim3 og(DMODEL / 128, (2 * SEQ) / 128);
    outgemm_kernel<<<og, 256, 0, stream>>>(A0h, Woh, out_attn);
}

// Round 13
// 511.982 us; speedup vs baseline: 1.1262x; 1.1262x over previous
//
#include <hip/hip_runtime.h>

typedef __attribute__((ext_vector_type(8))) _Float16 half8;
typedef __attribute__((ext_vector_type(4))) _Float16 half4;
typedef __attribute__((ext_vector_type(4))) float f32x4;

#define SEQ 2048
#define DMODEL 1024
#define NHEAD 16
#define HEADD 64
#define NBH 32          // B * NHEAD
#define LUTW 4096

__device__ __forceinline__ void nt_store_f4(float* p, f32x4 v) {
    __builtin_nontemporal_store(v, (f32x4*)p);
}

// raw barrier: orders LDS only; global loads/stores stay in flight across it
#define LDS_BAR() do {                                   \
    __builtin_amdgcn_sched_barrier(0);                   \
    asm volatile("s_waitcnt lgkmcnt(0)" ::: "memory");   \
    __builtin_amdgcn_sched_barrier(0);                   \
    __builtin_amdgcn_s_barrier();                        \
    __builtin_amdgcn_sched_barrier(0);                   \
} while (0)

// ---------------- T5 relative position bucket ----------------
__device__ __forceinline__ int rel_bucket(int rel) {
    int ret = (rel > 0) ? 16 : 0;
    int rp = rel < 0 ? -rel : rel;
    if (rp < 8) return ret + rp;
    float x = logf((float)rp * 0.125f) / 2.7725887f * 8.0f;
    int v = 8 + (int)x;
    v = v < 15 ? v : 15;
    return ret + v;
}

// ---------------- prep: all casts + bias LUT in one launch ----------------
__global__ __launch_bounds__(256) void prep_kernel(const float* __restrict__ hs,
                                                   const float* __restrict__ Wq,
                                                   const float* __restrict__ Wk,
                                                   const float* __restrict__ Wv,
                                                   const float* __restrict__ Wo,
                                                   const float* __restrict__ rel_bias,
                                                   _Float16* __restrict__ Xh,
                                                   _Float16* __restrict__ Wqh,
                                                   _Float16* __restrict__ Wkh,
                                                   _Float16* __restrict__ Wvh,
                                                   _Float16* __restrict__ Woh,
                                                   float* __restrict__ lut) {
    int bid = blockIdx.x;
    if (bid < 4096) {
        const float* in;
        _Float16* out;
        int base;
        if (bid < 2048)      { in = hs; out = Xh;  base = bid; }
        else if (bid < 2560) { in = Wq; out = Wqh; base = bid - 2048; }
        else if (bid < 3072) { in = Wk; out = Wkh; base = bid - 2560; }
        else if (bid < 3584) { in = Wv; out = Wvh; base = bid - 3072; }
        else                 { in = Wo; out = Woh; base = bid - 3584; }
        int i = (base * 256 + threadIdx.x) * 8;
        f32x4 a = *(const f32x4*)(in + i);
        f32x4 b = *(const f32x4*)(in + i + 4);
        half8 r;
        r[0] = (_Float16)a[0]; r[1] = (_Float16)a[1];
        r[2] = (_Float16)a[2]; r[3] = (_Float16)a[3];
        r[4] = (_Float16)b[0]; r[5] = (_Float16)b[1];
        r[6] = (_Float16)b[2]; r[7] = (_Float16)b[3];
        *(half8*)(out + i) = r;
    } else {
        int i = (bid - 4096) * 256 + threadIdx.x;   // 16 * 4096
        int h = i >> 12;
        int idx = i & (LUTW - 1);
        int rel = idx - 2047;
        int b = rel_bucket(rel);
        lut[i] = rel_bias[b * NHEAD + h];
    }
}

// ---------------- fused Q/K/V projection: direct-global (L2-resident inputs) ----------------
__global__ __launch_bounds__(256) void proj3_kernel(const _Float16* __restrict__ Xh,
                                                    const _Float16* __restrict__ Wqh,
                                                    const _Float16* __restrict__ Wkh,
                                                    const _Float16* __restrict__ Wvh,
                                                    _Float16* __restrict__ Qh,
                                                    _Float16* __restrict__ Kh,
                                                    _Float16* __restrict__ Vt) {
    int z = blockIdx.z;
    const _Float16* B = (z == 0) ? Wqh : (z == 1) ? Wkh : Wvh;
    int l = threadIdx.x & 63, w = threadIdx.x >> 6;
    int row0 = blockIdx.y * 128 + (w >> 1) * 64;
    int col0 = blockIdx.x * 128 + (w & 1) * 64;
    int ar = l & 15, ak = (l >> 4) * 8;
    f32x4 acc[4][4] = {};
    for (int k0 = 0; k0 < DMODEL; k0 += 32) {
        half8 af[4], bf[4];
#pragma unroll
        for (int mi = 0; mi < 4; mi++)
            af[mi] = *(const half8*)(Xh + (size_t)(row0 + mi * 16 + ar) * DMODEL + k0 + ak);
#pragma unroll
        for (int ni = 0; ni < 4; ni++)
            bf[ni] = *(const half8*)(B + (size_t)(col0 + ni * 16 + ar) * DMODEL + k0 + ak);
#pragma unroll
        for (int mi = 0; mi < 4; mi++)
#pragma unroll
            for (int ni = 0; ni < 4; ni++)
                acc[mi][ni] = __builtin_amdgcn_mfma_f32_16x16x32_f16(af[mi], bf[ni], acc[mi][ni], 0, 0, 0);
    }
    int cr = (l >> 4) * 4, cc = l & 15;
    if (z < 2) {
        _Float16* C = z == 0 ? Qh : Kh;
#pragma unroll
        for (int mi = 0; mi < 4; mi++)
#pragma unroll
            for (int ni = 0; ni < 4; ni++) {
                int c = col0 + ni * 16 + cc;
#pragma unroll
                for (int j = 0; j < 4; j++)
                    C[(size_t)(row0 + mi * 16 + cr + j) * DMODEL + c] = (_Float16)acc[mi][ni][j];
            }
    } else {
#pragma unroll
        for (int mi = 0; mi < 4; mi++)
#pragma unroll
            for (int ni = 0; ni < 4; ni++) {
                int c = col0 + ni * 16 + cc;
                int h = c >> 6, hd = c & 63;
                int r = row0 + mi * 16 + cr;
                int b = r >> 11, s0 = r & 2047;
                half4 pk;
#pragma unroll
                for (int j = 0; j < 4; j++) pk[j] = (_Float16)acc[mi][ni][j];
                *(half4*)(Vt + (size_t)((b * NHEAD + h) * HEADD + hd) * SEQ + s0) = pk;
            }
    }
}

// ---------------- output projection: direct-global, fp32 C ----------------
__global__ __launch_bounds__(256) void outgemm_kernel(const _Float16* __restrict__ A,
                                                      const _Float16* __restrict__ B,
                                                      float* __restrict__ C) {
    int l = threadIdx.x & 63, w = threadIdx.x >> 6;
    int row0 = blockIdx.y * 128 + (w >> 1) * 64;
    int col0 = blockIdx.x * 128 + (w & 1) * 64;
    int ar = l & 15, ak = (l >> 4) * 8;
    f32x4 acc[4][4] = {};
    for (int k0 = 0; k0 < DMODEL; k0 += 32) {
        half8 af[4], bf[4];
#pragma unroll
        for (int mi = 0; mi < 4; mi++)
            af[mi] = *(const half8*)(A + (size_t)(row0 + mi * 16 + ar) * DMODEL + k0 + ak);
#pragma unroll
        for (int ni = 0; ni < 4; ni++)
            bf[ni] = *(const half8*)(B + (size_t)(col0 + ni * 16 + ar) * DMODEL + k0 + ak);
#pragma unroll
        for (int mi = 0; mi < 4; mi++)
#pragma unroll
            for (int ni = 0; ni < 4; ni++)
                acc[mi][ni] = __builtin_amdgcn_mfma_f32_16x16x32_f16(af[mi], bf[ni], acc[mi][ni], 0, 0, 0);
    }
    int cr = (l >> 4) * 4, cc = l & 15;
#pragma unroll
    for (int mi = 0; mi < 4; mi++)
#pragma unroll
        for (int ni = 0; ni < 4; ni++) {
            int c = col0 + ni * 16 + cc;
#pragma unroll
            for (int j = 0; j < 4; j++)
                C[(size_t)(row0 + mi * 16 + cr + j) * DMODEL + c] = acc[mi][ni][j];
        }
}

// ---------------- fused attention (R8 structure, nt stores; no-max softmax; balanced posbias) ----------------
// no-max: q·k ~ N(0,8) over 64 dims -> |s|max ~ 47 << 88; exp(s) safe fp32; masked -> 0 exactly.
__global__ __launch_bounds__(256) void attn_kernel(const _Float16* __restrict__ Q,
                                                   const _Float16* __restrict__ Kg,
                                                   const _Float16* __restrict__ Vg,
                                                   const float* __restrict__ lut,
                                                   const int* __restrict__ mask,
                                                   float* __restrict__ wts,
                                                   float* __restrict__ posb,
                                                   _Float16* __restrict__ attn0) {
    __shared__ _Float16 Kt[64][68];     // padded: conflict-free
    __shared__ _Float16 Vl[64][68];
    __shared__ _Float16 Pl[4][16][72];  // per-wave P staging
    int tid = threadIdx.x;
    int l = tid & 63, w = tid >> 6;
    int bid = blockIdx.x;               // 1024 blocks
    int xcd = bid & 7, idx = bid >> 3;
    int bh = (idx >> 5) * 8 + xcd;      // XCD-pinned K/V
    int qblk = idx & 31;
    int b = bh >> 4, h = bh & 15;
    int qbase = qblk * 64 + w * 16;
    size_t hoff = (size_t)(b * SEQ) * DMODEL + h * HEADD;
    int ar = l & 15, g = l >> 4, ak = g * 8;
    const float* luth = lut + h * LUTW;
    float* ob = wts + (size_t)bh * SEQ * SEQ;
    int q = qbase + ar;

    int sr = tid >> 2, sc = (tid & 3) * 16;
    const _Float16* Ksrc = Kg + hoff + sc;
    const _Float16* Vsrc = Vg + ((size_t)bh * HEADD + sr) * SEQ + sc;

    half8 qf[2];
#pragma unroll
    for (int kk = 0; kk < 2; kk++)
        qf[kk] = *(const half8*)(Q + hoff + (size_t)q * DMODEL + kk * 32 + ak);

    // ---------- phase 1: denominator sum (no max tracking) ----------
    half8 s0 = *(const half8*)(Ksrc + (size_t)sr * DMODEL);
    half8 s1 = *(const half8*)(Ksrc + (size_t)sr * DMODEL + 8);
    float lsum = 0.f;
    for (int k0 = 0; k0 < SEQ; k0 += 64) {
        *(half8*)&Kt[sr][sc] = s0;
        *(half8*)&Kt[sr][sc + 8] = s1;
        LDS_BAR();
        if (k0 + 64 < SEQ) {   // issue next K tile early; spans the barriers
            s0 = *(const half8*)(Ksrc + (size_t)(k0 + 64 + sr) * DMODEL);
            s1 = *(const half8*)(Ksrc + (size_t)(k0 + 64 + sr) * DMODEL + 8);
        }
        f32x4 acc[4] = {};
#pragma unroll
        for (int ni = 0; ni < 4; ni++)
#pragma unroll
            for (int kk = 0; kk < 2; kk++) {
                half8 kf = *(const half8*)&Kt[ni * 16 + ar][kk * 32 + ak];
                acc[ni] = __builtin_amdgcn_mfma_f32_16x16x32_f16(kf, qf[kk], acc[ni], 0, 0, 0);
            }
        LDS_BAR();
        float p0 = 0.f, p1 = 0.f, p2 = 0.f, p3 = 0.f;
#pragma unroll
        for (int ni = 0; ni < 4; ni++) {
            int kcol = k0 + ni * 16 + g * 4;
            int4 mk = *(const int4*)(mask + b * SEQ + kcol);
            const int* mp = (const int*)&mk;
            f32x4 lb4;
            __builtin_memcpy(&lb4, luth + kcol - q + 2047, 16);
            p0 += mp[0] ? __expf(acc[ni][0] + lb4[0]) : 0.f;
            p1 += mp[1] ? __expf(acc[ni][1] + lb4[1]) : 0.f;
            p2 += mp[2] ? __expf(acc[ni][2] + lb4[2]) : 0.f;
            p3 += mp[3] ? __expf(acc[ni][3] + lb4[3]) : 0.f;
        }
        lsum += (p0 + p1) + (p2 + p3);
    }
    // prefetch phase-2 tile 0 (K and V) before the cross-lane reduction
    half8 t0 = *(const half8*)(Ksrc + (size_t)sr * DMODEL);
    half8 t1 = *(const half8*)(Ksrc + (size_t)sr * DMODEL + 8);
    half8 v0 = *(const half8*)(Vsrc);
    half8 v1 = *(const half8*)(Vsrc + 8);
    lsum += __shfl_xor(lsum, 16);
    lsum += __shfl_xor(lsum, 32);
    float invl = 1.0f / lsum;
    LDS_BAR();   // phase boundary: all waves done with phase-1 Kt

    // ---------- phase 2: recompute -> weights (+posbias) + PV ----------
    f32x4 oacc[4] = {};
    for (int k0 = 0; k0 < SEQ; k0 += 64) {
        *(half8*)&Kt[sr][sc] = t0;
        *(half8*)&Kt[sr][sc + 8] = t1;
        *(half8*)&Vl[sr][sc] = v0;
        *(half8*)&Vl[sr][sc + 8] = v1;
        LDS_BAR();
        if (k0 + 64 < SEQ) {   // issue next K+V tiles early; spans barriers
            t0 = *(const half8*)(Ksrc + (size_t)(k0 + 64 + sr) * DMODEL);
            t1 = *(const half8*)(Ksrc + (size_t)(k0 + 64 + sr) * DMODEL + 8);
            v0 = *(const half8*)(Vsrc + k0 + 64);
            v1 = *(const half8*)(Vsrc + k0 + 64 + 8);
        }
        f32x4 acc[4] = {};
#pragma unroll
        for (int ni = 0; ni < 4; ni++)
#pragma unroll
            for (int kk = 0; kk < 2; kk++) {
                half8 kf = *(const half8*)&Kt[ni * 16 + ar][kk * 32 + ak];
                acc[ni] = __builtin_amdgcn_mfma_f32_16x16x32_f16(kf, qf[kk], acc[ni], 0, 0, 0);
            }
        int pbsel = (k0 < SEQ / 2) ? 0 : 1;   // balance posbias stores across b
#pragma unroll
        for (int ni = 0; ni < 4; ni++) {
            int kcol = k0 + ni * 16 + g * 4;
            int4 mk = *(const int4*)(mask + b * SEQ + kcol);
            const int* mp = (const int*)&mk;
            f32x4 lb4;
            __builtin_memcpy(&lb4, luth + kcol - q + 2047, 16);
            f32x4 wv;
#pragma unroll
            for (int j = 0; j < 4; j++)
                wv[j] = mp[j] ? __expf(acc[ni][j] + lb4[j]) * invl : 0.f;
            nt_store_f4(ob + (size_t)q * SEQ + kcol, wv);
            if (b == pbsel)
                nt_store_f4(posb + (size_t)h * SEQ * SEQ + (size_t)q * SEQ + kcol, lb4);
            half4 ph;
#pragma unroll
            for (int j = 0; j < 4; j++) ph[j] = (_Float16)wv[j];
            *(half4*)&Pl[w][ar][ni * 16 + g * 4] = ph;
        }
        // PV: O[q,hd] += P[q,s] * V[s,hd]  (V from LDS)
#pragma unroll
        for (int kk2 = 0; kk2 < 2; kk2++) {
            half8 pa = *(half8*)&Pl[w][ar][kk2 * 32 + g * 8];
#pragma unroll
            for (int ni = 0; ni < 4; ni++) {
                half8 vf = *(const half8*)&Vl[ni * 16 + ar][kk2 * 32 + g * 8];
                oacc[ni] = __builtin_amdgcn_mfma_f32_16x16x32_f16(pa, vf, oacc[ni], 0, 0, 0);
            }
        }
        LDS_BAR();
    }
#pragma unroll
    for (int ni = 0; ni < 4; ni++)
#pragma unroll
        for (int j = 0; j < 4; j++)
            attn0[(size_t)(b * SEQ + qbase + g * 4 + j) * DMODEL + h * HEADD + ni * 16 + ar] =
                (_Float16)oacc[ni][j];
}

extern "C" void kernel_launch(void* const* d_in, const int* in_sizes, int n_in,
                              void* d_out, int out_size, void* d_ws, size_t ws_size,
                              hipStream_t stream) {
    const float* hs = (const float*)d_in[0];
    const int* mask = (const int*)d_in[1];
    const float* Wq = (const float*)d_in[2];
    const float* Wk = (const float*)d_in[3];
    const float* Wv = (const float*)d_in[4];
    const float* Wo = (const float*)d_in[5];
    const float* rel_bias = (const float*)d_in[6];

    float* out_attn = (float*)d_out;                       // [2,2048,1024]
    float* out_wts = out_attn + (size_t)2 * SEQ * DMODEL;  // [2,16,2048,2048]
    float* out_posb = out_wts + (size_t)NBH * SEQ * SEQ;   // [1,16,2048,2048]

    char* ws = (char*)d_ws;
    size_t off = 0;
    auto carve = [&](size_t bytes) { void* p = ws + off; off += (bytes + 255) & ~(size_t)255; return p; };
    _Float16* Xh  = (_Float16*)carve((size_t)2 * SEQ * DMODEL * 2);
    _Float16* Wqh = (_Float16*)carve((size_t)DMODEL * DMODEL * 2);
    _Float16* Wkh = (_Float16*)carve((size_t)DMODEL * DMODEL * 2);
    _Float16* Wvh = (_Float16*)carve((size_t)DMODEL * DMODEL * 2);
    _Float16* Woh = (_Float16*)carve((size_t)DMODEL * DMODEL * 2);
    _Float16* Qh  = (_Float16*)carve((size_t)2 * SEQ * DMODEL * 2);
    _Float16* Kh  = (_Float16*)carve((size_t)2 * SEQ * DMODEL * 2);
    _Float16* Vt  = (_Float16*)carve((size_t)NBH * HEADD * SEQ * 2);
    _Float16* A0h = (_Float16*)carve((size_t)2 * SEQ * DMODEL * 2);
    float* lut    = (float*)carve((size_t)NHEAD * LUTW * 4);

    // 1. prep: casts + lut
    prep_kernel<<<4352, 256, 0, stream>>>(hs, Wq, Wk, Wv, Wo, rel_bias,
                                          Xh, Wqh, Wkh, Wvh, Woh, lut);

    // 2. Q/K/V projections (direct-global GEMM; inputs L2-resident)
    dim3 pg(DMODEL / 128, (2 * SEQ) / 128, 3);
    proj3_kernel<<<pg, 256, 0, stream>>>(Xh, Wqh, Wkh, Wvh, Qh, Kh, Vt);

    // 3. fused attention
    attn_kernel<<<1024, 256, 0, stream>>>(Qh, Kh, Vt, lut, mask, out_wts, out_posb, A0h);

    // 4. output projection (direct-global GEMM)
    dim3 og(DMODEL / 128, (2 * SEQ) / 128);
    outgemm_kernel<<<og, 256, 0, stream>>>(A0h, Woh, out_attn);
}

// Round 14
// 454.439 us; speedup vs baseline: 1.2689x; 1.1266x over previous
//
#include <hip/hip_runtime.h>

typedef __attribute__((ext_vector_type(8))) _Float16 half8;
typedef __attribute__((ext_vector_type(4))) _Float16 half4;
typedef __attribute__((ext_vector_type(4))) float f32x4;

#define SEQ 2048
#define DMODEL 1024
#define NHEAD 16
#define HEADD 64
#define NBH 32          // B * NHEAD
#define LUTW 4096

__device__ __forceinline__ void nt_store_f4(float* p, f32x4 v) {
    __builtin_nontemporal_store(v, (f32x4*)p);
}

// raw barrier: orders LDS only; global loads/stores stay in flight across it
#define LDS_BAR() do {                                   \
    __builtin_amdgcn_sched_barrier(0);                   \
    asm volatile("s_waitcnt lgkmcnt(0)" ::: "memory");   \
    __builtin_amdgcn_sched_barrier(0);                   \
    __builtin_amdgcn_s_barrier();                        \
    __builtin_amdgcn_sched_barrier(0);                   \
} while (0)

// ---------------- T5 relative position bucket ----------------
__device__ __forceinline__ int rel_bucket(int rel) {
    int ret = (rel > 0) ? 16 : 0;
    int rp = rel < 0 ? -rel : rel;
    if (rp < 8) return ret + rp;
    float x = logf((float)rp * 0.125f) / 2.7725887f * 8.0f;
    int v = 8 + (int)x;
    v = v < 15 ? v : 15;
    return ret + v;
}

// ---------------- prep: all casts + bias LUT in one launch ----------------
__global__ __launch_bounds__(256) void prep_kernel(const float* __restrict__ hs,
                                                   const float* __restrict__ Wq,
                                                   const float* __restrict__ Wk,
                                                   const float* __restrict__ Wv,
                                                   const float* __restrict__ Wo,
                                                   const float* __restrict__ rel_bias,
                                                   _Float16* __restrict__ Xh,
                                                   _Float16* __restrict__ Wqh,
                                                   _Float16* __restrict__ Wkh,
                                                   _Float16* __restrict__ Wvh,
                                                   _Float16* __restrict__ Woh,
                                                   float* __restrict__ lut) {
    int bid = blockIdx.x;
    if (bid < 4096) {
        const float* in;
        _Float16* out;
        int base;
        if (bid < 2048)      { in = hs; out = Xh;  base = bid; }
        else if (bid < 2560) { in = Wq; out = Wqh; base = bid - 2048; }
        else if (bid < 3072) { in = Wk; out = Wkh; base = bid - 2560; }
        else if (bid < 3584) { in = Wv; out = Wvh; base = bid - 3072; }
        else                 { in = Wo; out = Woh; base = bid - 3584; }
        int i = (base * 256 + threadIdx.x) * 8;
        f32x4 a = *(const f32x4*)(in + i);
        f32x4 b = *(const f32x4*)(in + i + 4);
        half8 r;
        r[0] = (_Float16)a[0]; r[1] = (_Float16)a[1];
        r[2] = (_Float16)a[2]; r[3] = (_Float16)a[3];
        r[4] = (_Float16)b[0]; r[5] = (_Float16)b[1];
        r[6] = (_Float16)b[2]; r[7] = (_Float16)b[3];
        *(half8*)(out + i) = r;
    } else {
        int i = (bid - 4096) * 256 + threadIdx.x;   // 16 * 4096
        int h = i >> 12;
        int idx = i & (LUTW - 1);
        int rel = idx - 2047;
        int b = rel_bucket(rel);
        lut[i] = rel_bias[b * NHEAD + h];
    }
}

// ---------------- fused Q/K/V projection + posbias writer ----------------
// z = 0(Q) 1(K) 2(V->Vt) 3(posbias stream, overlaps GEMM compute)
__global__ __launch_bounds__(256) void proj3_kernel(const _Float16* __restrict__ Xh,
                                                    const _Float16* __restrict__ Wqh,
                                                    const _Float16* __restrict__ Wkh,
                                                    const _Float16* __restrict__ Wvh,
                                                    _Float16* __restrict__ Qh,
                                                    _Float16* __restrict__ Kh,
                                                    _Float16* __restrict__ Vt,
                                                    const float* __restrict__ lut,
                                                    float* __restrict__ posb) {
    int z = blockIdx.z;
    if (z == 3) {
        // posbias: [1,16,2048,2048] via grid-stride, lut L1/L2-hot, nt stores
        int flat = blockIdx.y * 8 + blockIdx.x;        // 0..255
        const size_t total = (size_t)NHEAD * SEQ * SEQ / 4;   // 16,777,216 float4
        for (size_t idx = (size_t)flat * 256 + threadIdx.x; idx < total; idx += 65536) {
            size_t e = idx * 4;
            int k = (int)(e & 2047);
            int q = (int)((e >> 11) & 2047);
            int h = (int)(e >> 22);
            f32x4 v;
            __builtin_memcpy(&v, lut + h * LUTW + (k - q + 2047), 16);
            nt_store_f4(posb + e, v);
        }
        return;
    }
    const _Float16* B = (z == 0) ? Wqh : (z == 1) ? Wkh : Wvh;
    int l = threadIdx.x & 63, w = threadIdx.x >> 6;
    int row0 = blockIdx.y * 128 + (w >> 1) * 64;
    int col0 = blockIdx.x * 128 + (w & 1) * 64;
    int ar = l & 15, ak = (l >> 4) * 8;
    f32x4 acc[4][4] = {};
    for (int k0 = 0; k0 < DMODEL; k0 += 32) {
        half8 af[4], bf[4];
#pragma unroll
        for (int mi = 0; mi < 4; mi++)
            af[mi] = *(const half8*)(Xh + (size_t)(row0 + mi * 16 + ar) * DMODEL + k0 + ak);
#pragma unroll
        for (int ni = 0; ni < 4; ni++)
            bf[ni] = *(const half8*)(B + (size_t)(col0 + ni * 16 + ar) * DMODEL + k0 + ak);
#pragma unroll
        for (int mi = 0; mi < 4; mi++)
#pragma unroll
            for (int ni = 0; ni < 4; ni++)
                acc[mi][ni] = __builtin_amdgcn_mfma_f32_16x16x32_f16(af[mi], bf[ni], acc[mi][ni], 0, 0, 0);
    }
    int cr = (l >> 4) * 4, cc = l & 15;
    if (z < 2) {
        _Float16* C = z == 0 ? Qh : Kh;
#pragma unroll
        for (int mi = 0; mi < 4; mi++)
#pragma unroll
            for (int ni = 0; ni < 4; ni++) {
                int c = col0 + ni * 16 + cc;
#pragma unroll
                for (int j = 0; j < 4; j++)
                    C[(size_t)(row0 + mi * 16 + cr + j) * DMODEL + c] = (_Float16)acc[mi][ni][j];
            }
    } else {
#pragma unroll
        for (int mi = 0; mi < 4; mi++)
#pragma unroll
            for (int ni = 0; ni < 4; ni++) {
                int c = col0 + ni * 16 + cc;
                int h = c >> 6, hd = c & 63;
                int r = row0 + mi * 16 + cr;
                int b = r >> 11, s0 = r & 2047;
                half4 pk;
#pragma unroll
                for (int j = 0; j < 4; j++) pk[j] = (_Float16)acc[mi][ni][j];
                *(half4*)(Vt + (size_t)((b * NHEAD + h) * HEADD + hd) * SEQ + s0) = pk;
            }
    }
}

// ---------------- output projection: direct-global, fp32 C ----------------
__global__ __launch_bounds__(256) void outgemm_kernel(const _Float16* __restrict__ A,
                                                      const _Float16* __restrict__ B,
                                                      float* __restrict__ C) {
    int l = threadIdx.x & 63, w = threadIdx.x >> 6;
    int row0 = blockIdx.y * 128 + (w >> 1) * 64;
    int col0 = blockIdx.x * 128 + (w & 1) * 64;
    int ar = l & 15, ak = (l >> 4) * 8;
    f32x4 acc[4][4] = {};
    for (int k0 = 0; k0 < DMODEL; k0 += 32) {
        half8 af[4], bf[4];
#pragma unroll
        for (int mi = 0; mi < 4; mi++)
            af[mi] = *(const half8*)(A + (size_t)(row0 + mi * 16 + ar) * DMODEL + k0 + ak);
#pragma unroll
        for (int ni = 0; ni < 4; ni++)
            bf[ni] = *(const half8*)(B + (size_t)(col0 + ni * 16 + ar) * DMODEL + k0 + ak);
#pragma unroll
        for (int mi = 0; mi < 4; mi++)
#pragma unroll
            for (int ni = 0; ni < 4; ni++)
                acc[mi][ni] = __builtin_amdgcn_mfma_f32_16x16x32_f16(af[mi], bf[ni], acc[mi][ni], 0, 0, 0);
    }
    int cr = (l >> 4) * 4, cc = l & 15;
#pragma unroll
    for (int mi = 0; mi < 4; mi++)
#pragma unroll
        for (int ni = 0; ni < 4; ni++) {
            int c = col0 + ni * 16 + cc;
#pragma unroll
            for (int j = 0; j < 4; j++)
                C[(size_t)(row0 + mi * 16 + cr + j) * DMODEL + c] = acc[mi][ni][j];
        }
}

// ---------------- fused attention (exact R8 structure, posbias removed) ----------------
__global__ __launch_bounds__(256) void attn_kernel(const _Float16* __restrict__ Q,
                                                   const _Float16* __restrict__ Kg,
                                                   const _Float16* __restrict__ Vg,
                                                   const float* __restrict__ lut,
                                                   const int* __restrict__ mask,
                                                   float* __restrict__ wts,
                                                   _Float16* __restrict__ attn0) {
    __shared__ _Float16 Kt[64][68];     // padded: conflict-free
    __shared__ _Float16 Vl[64][68];
    __shared__ _Float16 Pl[4][16][72];  // per-wave P staging
    int tid = threadIdx.x;
    int l = tid & 63, w = tid >> 6;
    int bid = blockIdx.x;               // 1024 blocks
    int xcd = bid & 7, idx = bid >> 3;
    int bh = (idx >> 5) * 8 + xcd;      // XCD-pinned K/V
    int qblk = idx & 31;
    int b = bh >> 4, h = bh & 15;
    int qbase = qblk * 64 + w * 16;
    size_t hoff = (size_t)(b * SEQ) * DMODEL + h * HEADD;
    int ar = l & 15, g = l >> 4, ak = g * 8;
    const float* luth = lut + h * LUTW;
    float* ob = wts + (size_t)bh * SEQ * SEQ;
    int q = qbase + ar;

    int sr = tid >> 2, sc = (tid & 3) * 16;
    const _Float16* Ksrc = Kg + hoff + sc;
    const _Float16* Vsrc = Vg + ((size_t)bh * HEADD + sr) * SEQ + sc;

    half8 qf[2];
#pragma unroll
    for (int kk = 0; kk < 2; kk++)
        qf[kk] = *(const half8*)(Q + hoff + (size_t)q * DMODEL + kk * 32 + ak);

    // ---------- phase 1: online per-row stats ----------
    half8 s0 = *(const half8*)(Ksrc + (size_t)sr * DMODEL);
    half8 s1 = *(const half8*)(Ksrc + (size_t)sr * DMODEL + 8);
    float m = -3e38f, lsum = 0.f;
    for (int k0 = 0; k0 < SEQ; k0 += 64) {
        *(half8*)&Kt[sr][sc] = s0;
        *(half8*)&Kt[sr][sc + 8] = s1;
        LDS_BAR();
        if (k0 + 64 < SEQ) {   // issue next K tile early; spans the barriers
            s0 = *(const half8*)(Ksrc + (size_t)(k0 + 64 + sr) * DMODEL);
            s1 = *(const half8*)(Ksrc + (size_t)(k0 + 64 + sr) * DMODEL + 8);
        }
        f32x4 acc[4] = {};
#pragma unroll
        for (int ni = 0; ni < 4; ni++)
#pragma unroll
            for (int kk = 0; kk < 2; kk++) {
                half8 kf = *(const half8*)&Kt[ni * 16 + ar][kk * 32 + ak];
                acc[ni] = __builtin_amdgcn_mfma_f32_16x16x32_f16(kf, qf[kk], acc[ni], 0, 0, 0);
            }
        LDS_BAR();
        float vv[16];
#pragma unroll
        for (int ni = 0; ni < 4; ni++) {
            int kcol = k0 + ni * 16 + g * 4;
            int4 mk = *(const int4*)(mask + b * SEQ + kcol);
            const int* mp = (const int*)&mk;
            f32x4 lb4;
            __builtin_memcpy(&lb4, luth + kcol - q + 2047, 16);
#pragma unroll
            for (int j = 0; j < 4; j++)
                vv[ni * 4 + j] = mp[j] ? (acc[ni][j] + lb4[j]) : -1e9f;
        }
        // tree max
        float t8[8];
#pragma unroll
        for (int t = 0; t < 8; t++) t8[t] = fmaxf(vv[t], vv[t + 8]);
        float t4a = fmaxf(t8[0], t8[4]), t4b = fmaxf(t8[1], t8[5]);
        float t4c = fmaxf(t8[2], t8[6]), t4d = fmaxf(t8[3], t8[7]);
        float vmax = fmaxf(fmaxf(t4a, t4b), fmaxf(t4c, t4d));
        float mn = fmaxf(m, vmax);
        float scale = __expf(m - mn);
        float e[16];
#pragma unroll
        for (int t = 0; t < 16; t++) e[t] = __expf(vv[t] - mn);
        float s8[8];
#pragma unroll
        for (int t = 0; t < 8; t++) s8[t] = e[t] + e[t + 8];
        float s4a = s8[0] + s8[4], s4b = s8[1] + s8[5];
        float s4c = s8[2] + s8[6], s4d = s8[3] + s8[7];
        float s = (s4a + s4b) + (s4c + s4d);
        lsum = lsum * scale + s;
        m = mn;
    }
    // prefetch phase-2 tile 0 (K and V) before the cross-lane reduction
    half8 t0 = *(const half8*)(Ksrc + (size_t)sr * DMODEL);
    half8 t1 = *(const half8*)(Ksrc + (size_t)sr * DMODEL + 8);
    half8 v0 = *(const half8*)(Vsrc);
    half8 v1 = *(const half8*)(Vsrc + 8);
#pragma unroll
    for (int off2 = 16; off2 <= 32; off2 <<= 1) {
        float mo = __shfl_xor(m, off2);
        float lo = __shfl_xor(lsum, off2);
        float mn = fmaxf(m, mo);
        lsum = lsum * __expf(m - mn) + lo * __expf(mo - mn);
        m = mn;
    }
    float invl = 1.0f / lsum;
    LDS_BAR();   // phase boundary: all waves done with phase-1 Kt

    // ---------- phase 2: recompute -> weights + PV ----------
    f32x4 oacc[4] = {};
    for (int k0 = 0; k0 < SEQ; k0 += 64) {
        *(half8*)&Kt[sr][sc] = t0;
        *(half8*)&Kt[sr][sc + 8] = t1;
        *(half8*)&Vl[sr][sc] = v0;
        *(half8*)&Vl[sr][sc + 8] = v1;
        LDS_BAR();
        if (k0 + 64 < SEQ) {   // issue next K+V tiles early; spans barriers
            t0 = *(const half8*)(Ksrc + (size_t)(k0 + 64 + sr) * DMODEL);
            t1 = *(const half8*)(Ksrc + (size_t)(k0 + 64 + sr) * DMODEL + 8);
            v0 = *(const half8*)(Vsrc + k0 + 64);
            v1 = *(const half8*)(Vsrc + k0 + 64 + 8);
        }
        f32x4 acc[4] = {};
#pragma unroll
        for (int ni = 0; ni < 4; ni++)
#pragma unroll
            for (int kk = 0; kk < 2; kk++) {
                half8 kf = *(const half8*)&Kt[ni * 16 + ar][kk * 32 + ak];
                acc[ni] = __builtin_amdgcn_mfma_f32_16x16x32_f16(kf, qf[kk], acc[ni], 0, 0, 0);
            }
#pragma unroll
        for (int ni = 0; ni < 4; ni++) {
            int kcol = k0 + ni * 16 + g * 4;
            int4 mk = *(const int4*)(mask + b * SEQ + kcol);
            const int* mp = (const int*)&mk;
            f32x4 lb4;
            __builtin_memcpy(&lb4, luth + kcol - q + 2047, 16);
            f32x4 wv;
#pragma unroll
            for (int j = 0; j < 4; j++) {
                float v = mp[j] ? (acc[ni][j] + lb4[j]) : -1e9f;
                wv[j] = __expf(v - m) * invl;
            }
            nt_store_f4(ob + (size_t)q * SEQ + kcol, wv);
            half4 ph;
#pragma unroll
            for (int j = 0; j < 4; j++) ph[j] = (_Float16)wv[j];
            *(half4*)&Pl[w][ar][ni * 16 + g * 4] = ph;
        }
        // PV: O[q,hd] += P[q,s] * V[s,hd]  (V from LDS)
#pragma unroll
        for (int kk2 = 0; kk2 < 2; kk2++) {
            half8 pa = *(half8*)&Pl[w][ar][kk2 * 32 + g * 8];
#pragma unroll
            for (int ni = 0; ni < 4; ni++) {
                half8 vf = *(const half8*)&Vl[ni * 16 + ar][kk2 * 32 + g * 8];
                oacc[ni] = __builtin_amdgcn_mfma_f32_16x16x32_f16(pa, vf, oacc[ni], 0, 0, 0);
            }
        }
        LDS_BAR();
    }
#pragma unroll
    for (int ni = 0; ni < 4; ni++)
#pragma unroll
        for (int j = 0; j < 4; j++)
            attn0[(size_t)(b * SEQ + qbase + g * 4 + j) * DMODEL + h * HEADD + ni * 16 + ar] =
                (_Float16)oacc[ni][j];
}

extern "C" void kernel_launch(void* const* d_in, const int* in_sizes, int n_in,
                              void* d_out, int out_size, void* d_ws, size_t ws_size,
                              hipStream_t stream) {
    const float* hs = (const float*)d_in[0];
    const int* mask = (const int*)d_in[1];
    const float* Wq = (const float*)d_in[2];
    const float* Wk = (const float*)d_in[3];
    const float* Wv = (const float*)d_in[4];
    const float* Wo = (const float*)d_in[5];
    const float* rel_bias = (const float*)d_in[6];

    float* out_attn = (float*)d_out;                       // [2,2048,1024]
    float* out_wts = out_attn + (size_t)2 * SEQ * DMODEL;  // [2,16,2048,2048]
    float* out_posb = out_wts + (size_t)NBH * SEQ * SEQ;   // [1,16,2048,2048]

    char* ws = (char*)d_ws;
    size_t off = 0;
    auto carve = [&](size_t bytes) { void* p = ws + off; off += (bytes + 255) & ~(size_t)255; return p; };
    _Float16* Xh  = (_Float16*)carve((size_t)2 * SEQ * DMODEL * 2);
    _Float16* Wqh = (_Float16*)carve((size_t)DMODEL * DMODEL * 2);
    _Float16* Wkh = (_Float16*)carve((size_t)DMODEL * DMODEL * 2);
    _Float16* Wvh = (_Float16*)carve((size_t)DMODEL * DMODEL * 2);
    _Float16* Woh = (_Float16*)carve((size_t)DMODEL * DMODEL * 2);
    _Float16* Qh  = (_Float16*)carve((size_t)2 * SEQ * DMODEL * 2);
    _Float16* Kh  = (_Float16*)carve((size_t)2 * SEQ * DMODEL * 2);
    _Float16* Vt  = (_Float16*)carve((size_t)NBH * HEADD * SEQ * 2);
    _Float16* A0h = (_Float16*)carve((size_t)2 * SEQ * DMODEL * 2);
    float* lut    = (float*)carve((size_t)NHEAD * LUTW * 4);

    // 1. prep: casts + lut
    prep_kernel<<<4352, 256, 0, stream>>>(hs, Wq, Wk, Wv, Wo, rel_bias,
                                          Xh, Wqh, Wkh, Wvh, Woh, lut);

    // 2. Q/K/V projections + posbias stream (overlapped in one launch)
    dim3 pg(DMODEL / 128, (2 * SEQ) / 128, 4);
    proj3_kernel<<<pg, 256, 0, stream>>>(Xh, Wqh, Wkh, Wvh, Qh, Kh, Vt, lut, out_posb);

    // 3. fused attention (weights + PV only)
    attn_kernel<<<1024, 256, 0, stream>>>(Qh, Kh, Vt, lut, mask, out_wts, A0h);

    // 4. output projection
    dim3 og(DMODEL / 128, (2 * SEQ) / 128);
    outgemm_kernel<<<og, 256, 0, stream>>>(A0h, Woh, out_attn);
}

// Round 15
// 442.687 us; speedup vs baseline: 1.3025x; 1.0265x over previous
//
#include <hip/hip_runtime.h>

typedef __attribute__((ext_vector_type(8))) _Float16 half8;
typedef __attribute__((ext_vector_type(4))) _Float16 half4;
typedef __attribute__((ext_vector_type(4))) float f32x4;

#define SEQ 2048
#define DMODEL 1024
#define NHEAD 16
#define HEADD 64
#define NBH 32          // B * NHEAD
#define LUTW 4096

__device__ __forceinline__ void nt_store_f4(float* p, f32x4 v) {
    __builtin_nontemporal_store(v, (f32x4*)p);
}

// raw barrier: orders LDS only; global loads/stores stay in flight across it
#define LDS_BAR() do {                                   \
    __builtin_amdgcn_sched_barrier(0);                   \
    asm volatile("s_waitcnt lgkmcnt(0)" ::: "memory");   \
    __builtin_amdgcn_sched_barrier(0);                   \
    __builtin_amdgcn_s_barrier();                        \
    __builtin_amdgcn_sched_barrier(0);                   \
} while (0)

// ---------------- T5 relative position bucket ----------------
__device__ __forceinline__ int rel_bucket(int rel) {
    int ret = (rel > 0) ? 16 : 0;
    int rp = rel < 0 ? -rel : rel;
    if (rp < 8) return ret + rp;
    float x = logf((float)rp * 0.125f) / 2.7725887f * 8.0f;
    int v = 8 + (int)x;
    v = v < 15 ? v : 15;
    return ret + v;
}

// ---------------- prep: all casts + bias LUT in one launch ----------------
__global__ __launch_bounds__(256) void prep_kernel(const float* __restrict__ hs,
                                                   const float* __restrict__ Wq,
                                                   const float* __restrict__ Wk,
                                                   const float* __restrict__ Wv,
                                                   const float* __restrict__ Wo,
                                                   const float* __restrict__ rel_bias,
                                                   _Float16* __restrict__ Xh,
                                                   _Float16* __restrict__ Wqh,
                                                   _Float16* __restrict__ Wkh,
                                                   _Float16* __restrict__ Wvh,
                                                   _Float16* __restrict__ Woh,
                                                   float* __restrict__ lut) {
    int bid = blockIdx.x;
    if (bid < 4096) {
        const float* in;
        _Float16* out;
        int base;
        if (bid < 2048)      { in = hs; out = Xh;  base = bid; }
        else if (bid < 2560) { in = Wq; out = Wqh; base = bid - 2048; }
        else if (bid < 3072) { in = Wk; out = Wkh; base = bid - 2560; }
        else if (bid < 3584) { in = Wv; out = Wvh; base = bid - 3072; }
        else                 { in = Wo; out = Woh; base = bid - 3584; }
        int i = (base * 256 + threadIdx.x) * 8;
        f32x4 a = *(const f32x4*)(in + i);
        f32x4 b = *(const f32x4*)(in + i + 4);
        half8 r;
        r[0] = (_Float16)a[0]; r[1] = (_Float16)a[1];
        r[2] = (_Float16)a[2]; r[3] = (_Float16)a[3];
        r[4] = (_Float16)b[0]; r[5] = (_Float16)b[1];
        r[6] = (_Float16)b[2]; r[7] = (_Float16)b[3];
        *(half8*)(out + i) = r;
    } else {
        int i = (bid - 4096) * 256 + threadIdx.x;   // 16 * 4096
        int h = i >> 12;
        int idx = i & (LUTW - 1);
        int rel = idx - 2047;
        int b = rel_bucket(rel);
        lut[i] = rel_bias[b * NHEAD + h];
    }
}

// ---------------- fused Q/K/V projection + posbias writer ----------------
// z = 0(Q) 1(K) 2(V->Vt) 3(posbias stream, overlaps GEMM compute)
__global__ __launch_bounds__(256) void proj3_kernel(const _Float16* __restrict__ Xh,
                                                    const _Float16* __restrict__ Wqh,
                                                    const _Float16* __restrict__ Wkh,
                                                    const _Float16* __restrict__ Wvh,
                                                    _Float16* __restrict__ Qh,
                                                    _Float16* __restrict__ Kh,
                                                    _Float16* __restrict__ Vt,
                                                    const float* __restrict__ lut,
                                                    float* __restrict__ posb) {
    int z = blockIdx.z;
    if (z == 3) {
        int flat = blockIdx.y * 8 + blockIdx.x;        // 0..255
        const size_t total = (size_t)NHEAD * SEQ * SEQ / 4;   // 16,777,216 float4
        for (size_t idx = (size_t)flat * 256 + threadIdx.x; idx < total; idx += 65536) {
            size_t e = idx * 4;
            int k = (int)(e & 2047);
            int q = (int)((e >> 11) & 2047);
            int h = (int)(e >> 22);
            f32x4 v;
            __builtin_memcpy(&v, lut + h * LUTW + (k - q + 2047), 16);
            nt_store_f4(posb + e, v);
        }
        return;
    }
    const _Float16* B = (z == 0) ? Wqh : (z == 1) ? Wkh : Wvh;
    int l = threadIdx.x & 63, w = threadIdx.x >> 6;
    int row0 = blockIdx.y * 128 + (w >> 1) * 64;
    int col0 = blockIdx.x * 128 + (w & 1) * 64;
    int ar = l & 15, ak = (l >> 4) * 8;
    f32x4 acc[4][4] = {};
    for (int k0 = 0; k0 < DMODEL; k0 += 32) {
        half8 af[4], bf[4];
#pragma unroll
        for (int mi = 0; mi < 4; mi++)
            af[mi] = *(const half8*)(Xh + (size_t)(row0 + mi * 16 + ar) * DMODEL + k0 + ak);
#pragma unroll
        for (int ni = 0; ni < 4; ni++)
            bf[ni] = *(const half8*)(B + (size_t)(col0 + ni * 16 + ar) * DMODEL + k0 + ak);
#pragma unroll
        for (int mi = 0; mi < 4; mi++)
#pragma unroll
            for (int ni = 0; ni < 4; ni++)
                acc[mi][ni] = __builtin_amdgcn_mfma_f32_16x16x32_f16(af[mi], bf[ni], acc[mi][ni], 0, 0, 0);
    }
    int cr = (l >> 4) * 4, cc = l & 15;
    if (z < 2) {
        _Float16* C = z == 0 ? Qh : Kh;
#pragma unroll
        for (int mi = 0; mi < 4; mi++)
#pragma unroll
            for (int ni = 0; ni < 4; ni++) {
                int c = col0 + ni * 16 + cc;
#pragma unroll
                for (int j = 0; j < 4; j++)
                    C[(size_t)(row0 + mi * 16 + cr + j) * DMODEL + c] = (_Float16)acc[mi][ni][j];
            }
    } else {
#pragma unroll
        for (int mi = 0; mi < 4; mi++)
#pragma unroll
            for (int ni = 0; ni < 4; ni++) {
                int c = col0 + ni * 16 + cc;
                int h = c >> 6, hd = c & 63;
                int r = row0 + mi * 16 + cr;
                int b = r >> 11, s0 = r & 2047;
                half4 pk;
#pragma unroll
                for (int j = 0; j < 4; j++) pk[j] = (_Float16)acc[mi][ni][j];
                *(half4*)(Vt + (size_t)((b * NHEAD + h) * HEADD + hd) * SEQ + s0) = pk;
            }
    }
}

// ---------------- output projection: direct-global, fp32 C ----------------
__global__ __launch_bounds__(256) void outgemm_kernel(const _Float16* __restrict__ A,
                                                      const _Float16* __restrict__ B,
                                                      float* __restrict__ C) {
    int l = threadIdx.x & 63, w = threadIdx.x >> 6;
    int row0 = blockIdx.y * 128 + (w >> 1) * 64;
    int col0 = blockIdx.x * 128 + (w & 1) * 64;
    int ar = l & 15, ak = (l >> 4) * 8;
    f32x4 acc[4][4] = {};
    for (int k0 = 0; k0 < DMODEL; k0 += 32) {
        half8 af[4], bf[4];
#pragma unroll
        for (int mi = 0; mi < 4; mi++)
            af[mi] = *(const half8*)(A + (size_t)(row0 + mi * 16 + ar) * DMODEL + k0 + ak);
#pragma unroll
        for (int ni = 0; ni < 4; ni++)
            bf[ni] = *(const half8*)(B + (size_t)(col0 + ni * 16 + ar) * DMODEL + k0 + ak);
#pragma unroll
        for (int mi = 0; mi < 4; mi++)
#pragma unroll
            for (int ni = 0; ni < 4; ni++)
                acc[mi][ni] = __builtin_amdgcn_mfma_f32_16x16x32_f16(af[mi], bf[ni], acc[mi][ni], 0, 0, 0);
    }
    int cr = (l >> 4) * 4, cc = l & 15;
#pragma unroll
    for (int mi = 0; mi < 4; mi++)
#pragma unroll
        for (int ni = 0; ni < 4; ni++) {
            int c = col0 + ni * 16 + cc;
#pragma unroll
            for (int j = 0; j < 4; j++)
                C[(size_t)(row0 + mi * 16 + cr + j) * DMODEL + c] = acc[mi][ni][j];
        }
}

// ---------------- fused attention: item-paired phase pipeline ----------------
// Each block owns TWO q-blocks (A,B) of the SAME bh. Timeline:
//   P1(A) stats -> MIDDLE { P2(A) stores+PV  ||  P1(B) stats } -> P2(B) stores+PV
// Middle packs B's compute under A's store drain; K/V tiles shared.
__global__ __launch_bounds__(256) void attn_kernel(const _Float16* __restrict__ Q,
                                                   const _Float16* __restrict__ Kg,
                                                   const _Float16* __restrict__ Vg,
                                                   const float* __restrict__ lut,
                                                   const int* __restrict__ mask,
                                                   float* __restrict__ wts,
                                                   _Float16* __restrict__ attn0) {
    __shared__ _Float16 Kt[64][68];
    __shared__ _Float16 Vl[64][68];
    __shared__ _Float16 Pl[4][16][72];
    int tid = threadIdx.x;
    int l = tid & 63, w = tid >> 6;
    int bid = blockIdx.x;               // 512 blocks
    int xcd = bid & 7, idx = bid >> 3;  // idx 0..63
    int bh = (idx >> 4) * 8 + xcd;      // XCD-pinned K/V (4 bh-groups x 8 xcd)
    int qpair = idx & 15;
    int b = bh >> 4, h = bh & 15;
    int qbaseA = qpair * 64 + w * 16;   // rows 0..1023
    int qbaseB = qbaseA + 1024;         // rows 1024..2047
    size_t hoff = (size_t)(b * SEQ) * DMODEL + h * HEADD;
    int ar = l & 15, g = l >> 4, ak = g * 8;
    const float* luth = lut + h * LUTW;
    float* ob = wts + (size_t)bh * SEQ * SEQ;
    int qA = qbaseA + ar;
    int qB = qbaseB + ar;

    int sr = tid >> 2, sc = (tid & 3) * 16;
    const _Float16* Ksrc = Kg + hoff + sc;
    const _Float16* Vsrc = Vg + ((size_t)bh * HEADD + sr) * SEQ + sc;

    half8 qfA[2], qfB[2];
#pragma unroll
    for (int kk = 0; kk < 2; kk++) {
        qfA[kk] = *(const half8*)(Q + hoff + (size_t)qA * DMODEL + kk * 32 + ak);
        qfB[kk] = *(const half8*)(Q + hoff + (size_t)qB * DMODEL + kk * 32 + ak);
    }

    // ---------- P1(A): online stats for A ----------
    half8 s0 = *(const half8*)(Ksrc + (size_t)sr * DMODEL);
    half8 s1 = *(const half8*)(Ksrc + (size_t)sr * DMODEL + 8);
    float mA = -3e38f, lsumA = 0.f;
    for (int k0 = 0; k0 < SEQ; k0 += 64) {
        *(half8*)&Kt[sr][sc] = s0;
        *(half8*)&Kt[sr][sc + 8] = s1;
        LDS_BAR();
        if (k0 + 64 < SEQ) {
            s0 = *(const half8*)(Ksrc + (size_t)(k0 + 64 + sr) * DMODEL);
            s1 = *(const half8*)(Ksrc + (size_t)(k0 + 64 + sr) * DMODEL + 8);
        }
        f32x4 acc[4] = {};
#pragma unroll
        for (int ni = 0; ni < 4; ni++)
#pragma unroll
            for (int kk = 0; kk < 2; kk++) {
                half8 kf = *(const half8*)&Kt[ni * 16 + ar][kk * 32 + ak];
                acc[ni] = __builtin_amdgcn_mfma_f32_16x16x32_f16(kf, qfA[kk], acc[ni], 0, 0, 0);
            }
        LDS_BAR();
        float vv[16];
#pragma unroll
        for (int ni = 0; ni < 4; ni++) {
            int kcol = k0 + ni * 16 + g * 4;
            int4 mk = *(const int4*)(mask + b * SEQ + kcol);
            const int* mp = (const int*)&mk;
            f32x4 lb4;
            __builtin_memcpy(&lb4, luth + kcol - qA + 2047, 16);
#pragma unroll
            for (int j = 0; j < 4; j++)
                vv[ni * 4 + j] = mp[j] ? (acc[ni][j] + lb4[j]) : -1e9f;
        }
        float t8[8];
#pragma unroll
        for (int t = 0; t < 8; t++) t8[t] = fmaxf(vv[t], vv[t + 8]);
        float t4a = fmaxf(t8[0], t8[4]), t4b = fmaxf(t8[1], t8[5]);
        float t4c = fmaxf(t8[2], t8[6]), t4d = fmaxf(t8[3], t8[7]);
        float vmax = fmaxf(fmaxf(t4a, t4b), fmaxf(t4c, t4d));
        float mn = fmaxf(mA, vmax);
        float scale = __expf(mA - mn);
        float e[16];
#pragma unroll
        for (int t = 0; t < 16; t++) e[t] = __expf(vv[t] - mn);
        float s8[8];
#pragma unroll
        for (int t = 0; t < 8; t++) s8[t] = e[t] + e[t + 8];
        float s4a = s8[0] + s8[4], s4b = s8[1] + s8[5];
        float s4c = s8[2] + s8[6], s4d = s8[3] + s8[7];
        lsumA = lsumA * scale + (s4a + s4b) + (s4c + s4d);
        mA = mn;
    }
    // prefetch middle tile 0 (K and V)
    half8 t0 = *(const half8*)(Ksrc + (size_t)sr * DMODEL);
    half8 t1 = *(const half8*)(Ksrc + (size_t)sr * DMODEL + 8);
    half8 v0 = *(const half8*)(Vsrc);
    half8 v1 = *(const half8*)(Vsrc + 8);
#pragma unroll
    for (int off2 = 16; off2 <= 32; off2 <<= 1) {
        float mo = __shfl_xor(mA, off2);
        float lo = __shfl_xor(lsumA, off2);
        float mn = fmaxf(mA, mo);
        lsumA = lsumA * __expf(mA - mn) + lo * __expf(mo - mn);
        mA = mn;
    }
    float invlA = 1.0f / lsumA;
    LDS_BAR();   // all waves done with P1(A) Kt

    // ---------- MIDDLE: P2(A) + P1(B) ----------
    f32x4 oaccA[4] = {};
    float mB = -3e38f, lsumB = 0.f;
    for (int k0 = 0; k0 < SEQ; k0 += 64) {
        *(half8*)&Kt[sr][sc] = t0;
        *(half8*)&Kt[sr][sc + 8] = t1;
        *(half8*)&Vl[sr][sc] = v0;
        *(half8*)&Vl[sr][sc + 8] = v1;
        LDS_BAR();
        if (k0 + 64 < SEQ) {
            t0 = *(const half8*)(Ksrc + (size_t)(k0 + 64 + sr) * DMODEL);
            t1 = *(const half8*)(Ksrc + (size_t)(k0 + 64 + sr) * DMODEL + 8);
            v0 = *(const half8*)(Vsrc + k0 + 64);
            v1 = *(const half8*)(Vsrc + k0 + 64 + 8);
        }
        f32x4 accA[4] = {}, accB[4] = {};
#pragma unroll
        for (int ni = 0; ni < 4; ni++)
#pragma unroll
            for (int kk = 0; kk < 2; kk++) {
                half8 kf = *(const half8*)&Kt[ni * 16 + ar][kk * 32 + ak];
                accA[ni] = __builtin_amdgcn_mfma_f32_16x16x32_f16(kf, qfA[kk], accA[ni], 0, 0, 0);
                accB[ni] = __builtin_amdgcn_mfma_f32_16x16x32_f16(kf, qfB[kk], accB[ni], 0, 0, 0);
            }
        // --- P2(A): weights + Pl ---
#pragma unroll
        for (int ni = 0; ni < 4; ni++) {
            int kcol = k0 + ni * 16 + g * 4;
            int4 mk = *(const int4*)(mask + b * SEQ + kcol);
            const int* mp = (const int*)&mk;
            f32x4 lb4;
            __builtin_memcpy(&lb4, luth + kcol - qA + 2047, 16);
            f32x4 wv;
#pragma unroll
            for (int j = 0; j < 4; j++) {
                float v = mp[j] ? (accA[ni][j] + lb4[j]) : -1e9f;
                wv[j] = __expf(v - mA) * invlA;
            }
            nt_store_f4(ob + (size_t)qA * SEQ + kcol, wv);
            half4 ph;
#pragma unroll
            for (int j = 0; j < 4; j++) ph[j] = (_Float16)wv[j];
            *(half4*)&Pl[w][ar][ni * 16 + g * 4] = ph;
        }
        // --- PV(A) ---
#pragma unroll
        for (int kk2 = 0; kk2 < 2; kk2++) {
            half8 pa = *(half8*)&Pl[w][ar][kk2 * 32 + g * 8];
#pragma unroll
            for (int ni = 0; ni < 4; ni++) {
                half8 vf = *(const half8*)&Vl[ni * 16 + ar][kk2 * 32 + g * 8];
                oaccA[ni] = __builtin_amdgcn_mfma_f32_16x16x32_f16(pa, vf, oaccA[ni], 0, 0, 0);
            }
        }
        // --- P1(B) stats (packs under A's store drain) ---
        {
            float vv[16];
#pragma unroll
            for (int ni = 0; ni < 4; ni++) {
                int kcol = k0 + ni * 16 + g * 4;
                int4 mk = *(const int4*)(mask + b * SEQ + kcol);
                const int* mp = (const int*)&mk;
                f32x4 lb4;
                __builtin_memcpy(&lb4, luth + kcol - qB + 2047, 16);
#pragma unroll
                for (int j = 0; j < 4; j++)
                    vv[ni * 4 + j] = mp[j] ? (accB[ni][j] + lb4[j]) : -1e9f;
            }
            float t8[8];
#pragma unroll
            for (int t = 0; t < 8; t++) t8[t] = fmaxf(vv[t], vv[t + 8]);
            float t4a = fmaxf(t8[0], t8[4]), t4b = fmaxf(t8[1], t8[5]);
            float t4c = fmaxf(t8[2], t8[6]), t4d = fmaxf(t8[3], t8[7]);
            float vmax = fmaxf(fmaxf(t4a, t4b), fmaxf(t4c, t4d));
            float mn = fmaxf(mB, vmax);
            float scale = __expf(mB - mn);
            float e[16];
#pragma unroll
            for (int t = 0; t < 16; t++) e[t] = __expf(vv[t] - mn);
            float s8[8];
#pragma unroll
            for (int t = 0; t < 8; t++) s8[t] = e[t] + e[t + 8];
            float s4a = s8[0] + s8[4], s4b = s8[1] + s8[5];
            float s4c = s8[2] + s8[6], s4d = s8[3] + s8[7];
            lsumB = lsumB * scale + (s4a + s4b) + (s4c + s4d);
            mB = mn;
        }
        LDS_BAR();
    }
    // write A's output rows
#pragma unroll
    for (int ni = 0; ni < 4; ni++)
#pragma unroll
        for (int j = 0; j < 4; j++)
            attn0[(size_t)(b * SEQ + qbaseA + g * 4 + j) * DMODEL + h * HEADD + ni * 16 + ar] =
                (_Float16)oaccA[ni][j];
    // prefetch P2(B) tile 0
    half8 u0 = *(const half8*)(Ksrc + (size_t)sr * DMODEL);
    half8 u1 = *(const half8*)(Ksrc + (size_t)sr * DMODEL + 8);
    half8 w0 = *(const half8*)(Vsrc);
    half8 w1 = *(const half8*)(Vsrc + 8);
#pragma unroll
    for (int off2 = 16; off2 <= 32; off2 <<= 1) {
        float mo = __shfl_xor(mB, off2);
        float lo = __shfl_xor(lsumB, off2);
        float mn = fmaxf(mB, mo);
        lsumB = lsumB * __expf(mB - mn) + lo * __expf(mo - mn);
        mB = mn;
    }
    float invlB = 1.0f / lsumB;
    LDS_BAR();

    // ---------- P2(B): weights + PV ----------
    f32x4 oaccB[4] = {};
    for (int k0 = 0; k0 < SEQ; k0 += 64) {
        *(half8*)&Kt[sr][sc] = u0;
        *(half8*)&Kt[sr][sc + 8] = u1;
        *(half8*)&Vl[sr][sc] = w0;
        *(half8*)&Vl[sr][sc + 8] = w1;
        LDS_BAR();
        if (k0 + 64 < SEQ) {
            u0 = *(const half8*)(Ksrc + (size_t)(k0 + 64 + sr) * DMODEL);
            u1 = *(const half8*)(Ksrc + (size_t)(k0 + 64 + sr) * DMODEL + 8);
            w0 = *(const half8*)(Vsrc + k0 + 64);
            w1 = *(const half8*)(Vsrc + k0 + 64 + 8);
        }
        f32x4 acc[4] = {};
#pragma unroll
        for (int ni = 0; ni < 4; ni++)
#pragma unroll
            for (int kk = 0; kk < 2; kk++) {
                half8 kf = *(const half8*)&Kt[ni * 16 + ar][kk * 32 + ak];
                acc[ni] = __builtin_amdgcn_mfma_f32_16x16x32_f16(kf, qfB[kk], acc[ni], 0, 0, 0);
            }
#pragma unroll
        for (int ni = 0; ni < 4; ni++) {
            int kcol = k0 + ni * 16 + g * 4;
            int4 mk = *(const int4*)(mask + b * SEQ + kcol);
            const int* mp = (const int*)&mk;
            f32x4 lb4;
            __builtin_memcpy(&lb4, luth + kcol - qB + 2047, 16);
            f32x4 wv;
#pragma unroll
            for (int j = 0; j < 4; j++) {
                float v = mp[j] ? (acc[ni][j] + lb4[j]) : -1e9f;
                wv[j] = __expf(v - mB) * invlB;
            }
            nt_store_f4(ob + (size_t)qB * SEQ + kcol, wv);
            half4 ph;
#pragma unroll
            for (int j = 0; j < 4; j++) ph[j] = (_Float16)wv[j];
            *(half4*)&Pl[w][ar][ni * 16 + g * 4] = ph;
        }
#pragma unroll
        for (int kk2 = 0; kk2 < 2; kk2++) {
            half8 pa = *(half8*)&Pl[w][ar][kk2 * 32 + g * 8];
#pragma unroll
            for (int ni = 0; ni < 4; ni++) {
                half8 vf = *(const half8*)&Vl[ni * 16 + ar][kk2 * 32 + g * 8];
                oaccB[ni] = __builtin_amdgcn_mfma_f32_16x16x32_f16(pa, vf, oaccB[ni], 0, 0, 0);
            }
        }
        LDS_BAR();
    }
#pragma unroll
    for (int ni = 0; ni < 4; ni++)
#pragma unroll
        for (int j = 0; j < 4; j++)
            attn0[(size_t)(b * SEQ + qbaseB + g * 4 + j) * DMODEL + h * HEADD + ni * 16 + ar] =
                (_Float16)oaccB[ni][j];
}

extern "C" void kernel_launch(void* const* d_in, const int* in_sizes, int n_in,
                              void* d_out, int out_size, void* d_ws, size_t ws_size,
                              hipStream_t stream) {
    const float* hs = (const float*)d_in[0];
    const int* mask = (const int*)d_in[1];
    const float* Wq = (const float*)d_in[2];
    const float* Wk = (const float*)d_in[3];
    const float* Wv = (const float*)d_in[4];
    const float* Wo = (const float*)d_in[5];
    const float* rel_bias = (const float*)d_in[6];

    float* out_attn = (float*)d_out;                       // [2,2048,1024]
    float* out_wts = out_attn + (size_t)2 * SEQ * DMODEL;  // [2,16,2048,2048]
    float* out_posb = out_wts + (size_t)NBH * SEQ * SEQ;   // [1,16,2048,2048]

    char* ws = (char*)d_ws;
    size_t off = 0;
    auto carve = [&](size_t bytes) { void* p = ws + off; off += (bytes + 255) & ~(size_t)255; return p; };
    _Float16* Xh  = (_Float16*)carve((size_t)2 * SEQ * DMODEL * 2);
    _Float16* Wqh = (_Float16*)carve((size_t)DMODEL * DMODEL * 2);
    _Float16* Wkh = (_Float16*)carve((size_t)DMODEL * DMODEL * 2);
    _Float16* Wvh = (_Float16*)carve((size_t)DMODEL * DMODEL * 2);
    _Float16* Woh = (_Float16*)carve((size_t)DMODEL * DMODEL * 2);
    _Float16* Qh  = (_Float16*)carve((size_t)2 * SEQ * DMODEL * 2);
    _Float16* Kh  = (_Float16*)carve((size_t)2 * SEQ * DMODEL * 2);
    _Float16* Vt  = (_Float16*)carve((size_t)NBH * HEADD * SEQ * 2);
    _Float16* A0h = (_Float16*)carve((size_t)2 * SEQ * DMODEL * 2);
    float* lut    = (float*)carve((size_t)NHEAD * LUTW * 4);

    // 1. prep: casts + lut
    prep_kernel<<<4352, 256, 0, stream>>>(hs, Wq, Wk, Wv, Wo, rel_bias,
                                          Xh, Wqh, Wkh, Wvh, Woh, lut);

    // 2. Q/K/V projections + posbias stream (overlapped in one launch)
    dim3 pg(DMODEL / 128, (2 * SEQ) / 128, 4);
    proj3_kernel<<<pg, 256, 0, stream>>>(Xh, Wqh, Wkh, Wvh, Qh, Kh, Vt, lut, out_posb);

    // 3. fused attention (item-paired pipeline, 512 blocks)
    attn_kernel<<<512, 256, 0, stream>>>(Qh, Kh, Vt, lut, mask, out_wts, A0h);

    // 4. output projection
    dim3 og(DMODEL / 128, (2 * SEQ) / 128);
    outgemm_kernel<<<og, 256, 0, stream>>>(A0h, Woh, out_attn);
}